// Round 11
// baseline (181.672 us; speedup 1.0000x reference)
//
#include <hip/hip_runtime.h>
#include <hip/hip_bf16.h>

// AttentivePooling: B=32, S=8192, C=256, MID=128, fp32 in/out.
// out[b,c] = sum_s softmax_s( tanh(x@W1+b1)@w2 )[b,s] * x[b,s,c]   (b2 shift-invariant)
//
// R11: persistent 1-block/CU pipeline. Each block streams 16 tiles (64 rows x
// 1KB = 64KB) through double-buffered LDS via global_load_lds; STAGE(t+1) is
// issued BEFORE waiting on t (counted vmcnt(16)) so the DMA queue never
// empties -> continuous HBM issue. LDS tile is FRAG-MAJOR (dest linear in
// lane => all ds_read_b128 conflict-free; per-lane global source does the
// transpose). Weighted sum is computed from the same LDS tile via 16-lane
// shfl reduction -> the K-loop contains NO vmem except the counted DMAs.

typedef __attribute__((ext_vector_type(8))) short short8;
typedef __attribute__((ext_vector_type(4))) float f32x4;
typedef unsigned short u16;

constexpr int Bb = 32;
constexpr int Ss = 8192;
constexpr int Cc = 256;
constexpr int MIDm = 128;
constexpr int TR   = 64;              // rows per tile
constexpr int TPB  = 16;              // tiles per block (persistent)
constexpr int NT   = Bb * Ss / TR;    // 4096 tiles
constexpr int GRID = NT / TPB;        // 256 blocks = 1 per CU
constexpr int BPB  = Ss / TR;         // 128 tiles per batch

__device__ __forceinline__ u16 f2bf(float f) {
  return __builtin_bit_cast(u16, __float2bfloat16(f));   // RNE
}

// ---- one-time prep: W fragments, frag-major ----
// FB[(kc*8+nt)*64 + lane] -> 8 bf16 (16B): n = nt*16+(lane&15), k = kc*32+(lane>>4)*8+e
__global__ __launch_bounds__(256) void wprep_kernel(
    const float* __restrict__ W1, u16* __restrict__ FB)
{
  const int t    = blockIdx.x * 256 + threadIdx.x;   // 0..4095
  const int lane = t & 63;
  const int nt   = (t >> 6) & 7;
  const int kc   = (t >> 9) & 7;
  const int n    = nt * 16 + (lane & 15);
  const int k0   = kc * 32 + (lane >> 4) * 8;
  union { u16 v[8]; short8 s; } u;
  #pragma unroll
  for (int e = 0; e < 8; ++e) u.v[e] = f2bf(W1[(size_t)(k0 + e) * MIDm + n]);
  *(short8*)(FB + (size_t)t * 8) = u.s;
}

// ---- fused persistent kernel ----
__global__ __launch_bounds__(256, 1) void fused_kernel(
    const float* __restrict__ x, const u16* __restrict__ FB,
    const float* __restrict__ b1, const float* __restrict__ w2,
    float* __restrict__ oPart, float* __restrict__ mPart, float* __restrict__ lPart)
{
  // 2 x 64KB frag-major x-tile buffers + small reduction arrays (~136KB total)
  __shared__ __align__(16) char xbuf[2 * 65536];
  __shared__ float sSc[4][TR];      // per-wave score partials
  __shared__ float sO[4][Cc];       // per-wave weighted-sum partials
  __shared__ float sP[TR];          // softmax exp weights
  __shared__ float sML[2];          // tile m, l

  const int tid  = threadIdx.x;
  const int lane = tid & 63;
  const int w    = tid >> 6;        // wave 0..3: owns cols n in [w*32, w*32+32)
  const int q    = lane >> 4;       // k-subgroup 0..3
  const int ln   = lane & 15;       // frag row/col index
  const int gt0  = blockIdx.x * TPB;

  // ---- prologue: preload W frags (this wave's 2 col-tiles), b1, w2 ----
  short8 Bf[8][2];
  #pragma unroll
  for (int kc = 0; kc < 8; ++kc)
    #pragma unroll
    for (int j = 0; j < 2; ++j)
      Bf[kc][j] = *(const short8*)(FB + ((size_t)((kc * 8 + (w * 2 + j)) * 64 + lane)) * 8);

  float b1v[2], w2v[2];
  #pragma unroll
  for (int j = 0; j < 2; ++j) {
    b1v[j] = b1[w * 32 + j * 16 + ln];
    w2v[j] = w2[w * 32 + j * 16 + ln];
  }

  // STAGE tile gt into buffer buf, frag-major:
  // LDS[(kc*4+mt)*2+half][lane] (1KB-per-idx, lane*16) <- x[gt*64+mt*16+ln][kc*32+q*8+half*4 ..+4]
  #define STAGE(buf, gt)                                                              \
    {                                                                                 \
      _Pragma("unroll")                                                               \
      for (int i = 0; i < 16; ++i) {                                                  \
        const int idx  = w * 16 + i;                                                  \
        const int kc_  = idx >> 3;                                                    \
        const int mt_  = (idx >> 1) & 3;                                              \
        const int hf_  = idx & 1;                                                     \
        const char* src = (const char*)x                                              \
            + (size_t)((gt) * TR + mt_ * 16 + ln) * 1024                              \
            + kc_ * 128 + q * 32 + hf_ * 16;                                          \
        __builtin_amdgcn_global_load_lds(                                             \
            (const __attribute__((address_space(1))) void*)src,                       \
            (__attribute__((address_space(3))) void*)                                 \
                (xbuf + (buf) * 65536 + idx * 1024 + lane * 16),                      \
            16, 0, 0);                                                                \
      }                                                                               \
    }

  STAGE(0, gt0);   // tile 0 in flight

  for (int t = 0; t < TPB; ++t) {
    const int cur = t & 1;
    const int gt  = gt0 + t;

    if (t < TPB - 1) STAGE(cur ^ 1, gt + 1);   // next tile: in flight through all of t

    __builtin_amdgcn_sched_barrier(0);
    if (t < TPB - 1) asm volatile("s_waitcnt vmcnt(16)" ::: "memory");  // t landed; t+1 flying
    else             asm volatile("s_waitcnt vmcnt(0)"  ::: "memory");
    __builtin_amdgcn_sched_barrier(0);
    __builtin_amdgcn_s_barrier();              // all waves' share of tile t visible
    __builtin_amdgcn_sched_barrier(0);

    const char* xb = xbuf + cur * 65536;

    // ---- GEMM: 64 rows x (this wave's 32 cols) x K=256; all ds_read lane-linear ----
    f32x4 acc[4][2];
    #pragma unroll
    for (int mt = 0; mt < 4; ++mt)
      #pragma unroll
      for (int j = 0; j < 2; ++j) {
        acc[mt][j][0] = b1v[j]; acc[mt][j][1] = b1v[j];
        acc[mt][j][2] = b1v[j]; acc[mt][j][3] = b1v[j];
      }

    #pragma unroll
    for (int kc = 0; kc < 8; ++kc)
      #pragma unroll
      for (int mt = 0; mt < 4; ++mt) {
        const char* fb = xb + kc * 8192 + mt * 2048 + lane * 16;
        float4 lo = *(const float4*)fb;
        float4 hi = *(const float4*)(fb + 1024);
        union { u16 v[8]; short8 s8; } t8;
        t8.v[0] = f2bf(lo.x); t8.v[1] = f2bf(lo.y); t8.v[2] = f2bf(lo.z); t8.v[3] = f2bf(lo.w);
        t8.v[4] = f2bf(hi.x); t8.v[5] = f2bf(hi.y); t8.v[6] = f2bf(hi.z); t8.v[7] = f2bf(hi.w);
        acc[mt][0] = __builtin_amdgcn_mfma_f32_16x16x32_bf16(t8.s8, Bf[kc][0], acc[mt][0], 0, 0, 0);
        acc[mt][1] = __builtin_amdgcn_mfma_f32_16x16x32_bf16(t8.s8, Bf[kc][1], acc[mt][1], 0, 0, 0);
      }

    // ---- scores: score[row] = sum_n tanh(h)*w2[n] (partial over this wave's 32 n) ----
    #pragma unroll
    for (int mt = 0; mt < 4; ++mt) {
      float p[4] = {0.f, 0.f, 0.f, 0.f};
      #pragma unroll
      for (int j = 0; j < 2; ++j)
        #pragma unroll
        for (int r = 0; r < 4; ++r)
          p[r] += (1.0f - 2.0f / (__expf(2.0f * acc[mt][j][r]) + 1.0f)) * w2v[j];
      #pragma unroll
      for (int off = 1; off < 16; off <<= 1)
        #pragma unroll
        for (int r = 0; r < 4; ++r) p[r] += __shfl_xor(p[r], off);
      if (ln == 0) {
        #pragma unroll
        for (int r = 0; r < 4; ++r) sSc[w][mt * 16 + q * 4 + r] = p[r];
      }
    }
    __syncthreads();

    // ---- tile softmax (wave 0, 64 rows) ----
    if (w == 0) {
      float v = sSc[0][lane] + sSc[1][lane] + sSc[2][lane] + sSc[3][lane];
      float m = v;
      #pragma unroll
      for (int off = 1; off < 64; off <<= 1) m = fmaxf(m, __shfl_xor(m, off));
      float e = __expf(v - m);
      float s = e;
      #pragma unroll
      for (int off = 1; off < 64; off <<= 1) s += __shfl_xor(s, off);
      sP[lane] = e;
      if (lane == 0) { sML[0] = m; sML[1] = s; }
    }
    __syncthreads();

    // ---- weighted sum from the SAME LDS tile (wave w covers rows w*16..w*16+15):
    //      lane reads its frag float4 (cols kc*32+q*8+half*4), scales by p[row],
    //      16-lane shfl reduce over ln accumulates the rows. No vmem here. ----
    {
      const float pw = sP[w * 16 + ln];
      #pragma unroll
      for (int kc = 0; kc < 8; ++kc)
        #pragma unroll
        for (int hf = 0; hf < 2; ++hf) {
          const char* fb = xb + kc * 8192 + w * 2048 + hf * 1024 + lane * 16;
          float4 v = *(const float4*)fb;
          v.x *= pw; v.y *= pw; v.z *= pw; v.w *= pw;
          #pragma unroll
          for (int off = 1; off < 16; off <<= 1) {
            v.x += __shfl_xor(v.x, off);
            v.y += __shfl_xor(v.y, off);
            v.z += __shfl_xor(v.z, off);
            v.w += __shfl_xor(v.w, off);
          }
          if (ln == 0) *(float4*)&sO[w][kc * 32 + q * 8 + hf * 4] = v;
        }
    }
    __syncthreads();

    // ---- reduce 4 wave-partials, store tile partial ----
    {
      float oc = sO[0][tid & 255] + sO[1][tid & 255] + sO[2][tid & 255] + sO[3][tid & 255];
      oPart[(size_t)gt * Cc + tid] = oc;
    }
    if (tid == 0) { mPart[gt] = sML[0]; lPart[gt] = sML[1]; }
  }
}

// ---- combine 128 tile-partials per batch (deterministic) ----
__global__ __launch_bounds__(256) void combine_kernel(
    const float* __restrict__ oPart, const float* __restrict__ mPart,
    const float* __restrict__ lPart, float* __restrict__ out)
{
  const int b = blockIdx.x;
  const int t = threadIdx.x;
  float M = -3.4e38f;
  for (int k = 0; k < BPB; ++k) M = fmaxf(M, mPart[b * BPB + k]);
  float num = 0.f, den = 0.f;
  for (int k = 0; k < BPB; ++k) {
    float wgt = __expf(mPart[b * BPB + k] - M);
    den += wgt * lPart[b * BPB + k];
    num = fmaf(wgt, oPart[(size_t)(b * BPB + k) * Cc + t], num);
  }
  out[b * Cc + t] = num / den;
}

extern "C" void kernel_launch(void* const* d_in, const int* in_sizes, int n_in,
                              void* d_out, int out_size, void* d_ws, size_t ws_size,
                              hipStream_t stream)
{
  const float* x  = (const float*)d_in[0];
  const float* W1 = (const float*)d_in[1];
  const float* b1 = (const float*)d_in[2];
  const float* w2 = (const float*)d_in[3];
  // d_in[4] = b2: unused (softmax shift-invariant)
  float* out = (float*)d_out;

  u16*   FB    = (u16*)d_ws;                                        // 64 KB
  float* oPart = (float*)((char*)d_ws + 65536);                     // 4 MB (4096x256)
  float* mPart = (float*)((char*)d_ws + 65536 + 4194304);           // 16 KB
  float* lPart = (float*)((char*)d_ws + 65536 + 4194304 + 16384);   // 16 KB

  wprep_kernel<<<16, 256, 0, stream>>>(W1, FB);
  fused_kernel<<<GRID, 256, 0, stream>>>(x, FB, b1, w2, oPart, mPart, lPart);
  combine_kernel<<<Bb, Cc, 0, stream>>>(oPart, mPart, lPart, out);
}

// Round 12
// 150.133 us; speedup vs baseline: 1.2101x; 1.2101x over previous
//
#include <hip/hip_runtime.h>
#include <hip/hip_bf16.h>

// AttentivePooling: B=32, S=8192, C=256, MID=128, fp32 in/out.
// out[b,c] = sum_s softmax_s( tanh(x@W1+b1)@w2 )[b,s] * x[b,s,c]   (b2 shift-invariant)
//
// R12: persistent steady-state pipeline. 512 blocks (2/CU) x 512 thr (16 waves/CU).
// Each block streams 16 tiles (32 rows x 1KB = 32KB) through double-buffered
// frag-major LDS via global_load_lds; STAGE(t+1) issued before vmcnt(4) wait on
// tile t -> the DMA queue never empties (HBM duty ~100%). All mid-loop barriers
// are raw s_barrier + lgkmcnt(0) (NO vmcnt drain). B-frags register-resident.
// Weighted sum re-reads the fp32 LDS tile (no global re-read, no bank conflicts).

typedef __attribute__((ext_vector_type(8))) short short8;
typedef __attribute__((ext_vector_type(4))) float f32x4;
typedef unsigned short u16;

constexpr int Bb = 32;
constexpr int Ss = 8192;
constexpr int Cc = 256;
constexpr int MIDm = 128;
constexpr int TR    = 32;                // rows per tile
constexpr int NTILE = Bb * Ss / TR;      // 8192
constexpr int GRID  = 512;               // 2 blocks per CU
constexpr int TPB   = NTILE / GRID;      // 16 tiles per block
constexpr int BPB   = Ss / TR;           // 256 tiles per batch

__device__ __forceinline__ u16 f2bf(float f) {
  return __builtin_bit_cast(u16, __float2bfloat16(f));   // RNE
}

// ---- one-time prep: W fragments, frag-major ----
// FB[(kc*8+nt)*64+lane] -> 8 bf16: n = nt*16+(lane&15), k = kc*32+(lane>>4)*8+e
__global__ __launch_bounds__(256) void wprep_kernel(
    const float* __restrict__ W1, u16* __restrict__ FB)
{
  const int t    = blockIdx.x * 256 + threadIdx.x;   // 0..4095
  const int lane = t & 63;
  const int nt   = (t >> 6) & 7;
  const int kc   = (t >> 9) & 7;
  const int n    = nt * 16 + (lane & 15);
  const int k0   = kc * 32 + (lane >> 4) * 8;
  union { u16 v[8]; short8 s; } u;
  #pragma unroll
  for (int e = 0; e < 8; ++e) u.v[e] = f2bf(W1[(size_t)(k0 + e) * MIDm + n]);
  *(short8*)(FB + (size_t)t * 8) = u.s;
}

// raw barrier: LDS-visibility only; DMA prefetch stays in flight (no vmcnt drain)
#define LBAR()                                                   \
  { __builtin_amdgcn_sched_barrier(0);                           \
    asm volatile("s_waitcnt lgkmcnt(0)" ::: "memory");           \
    __builtin_amdgcn_s_barrier();                                \
    __builtin_amdgcn_sched_barrier(0); }

// ---- fused persistent kernel ----
__global__ __launch_bounds__(512, 4) void fused_kernel(
    const float* __restrict__ x, const u16* __restrict__ FB,
    const float* __restrict__ b1, const float* __restrict__ w2,
    float* __restrict__ oPart, float* __restrict__ mPart, float* __restrict__ lPart)
{
  __shared__ __align__(16) char xbuf[2 * 32768];   // frag-major fp32 x tiles
  __shared__ float sSc[4][TR];                     // per-colquad score partials
  __shared__ float sP[TR];                         // softmax exp weights
  __shared__ float sO[2][Cc];                      // per-rowhalf weighted partials
  __shared__ float sML[2];

  const int tid  = threadIdx.x;
  const int lane = tid & 63;
  const int w    = tid >> 6;        // 8 waves
  const int rh   = w >> 2;          // row half  (rows rh*16 .. +16)
  const int cq   = w & 3;           // col quad  (cols cq*32 .. +32)
  const int q    = lane >> 4;
  const int ln   = lane & 15;
  const int gt0  = blockIdx.x * TPB;

  // ---- preload B frags (this wave's 2 col-16s), b1, w2 ----
  short8 Bf[8][2];
  #pragma unroll
  for (int kc = 0; kc < 8; ++kc)
    #pragma unroll
    for (int j = 0; j < 2; ++j)
      Bf[kc][j] = *(const short8*)(FB + ((size_t)((kc * 8 + cq * 2 + j) * 64 + lane)) * 8);
  float b1v[2], w2v[2];
  #pragma unroll
  for (int j = 0; j < 2; ++j) {
    b1v[j] = b1[cq * 32 + j * 16 + ln];
    w2v[j] = w2[cq * 32 + j * 16 + ln];
  }

  // STAGE tile gt into buffer buf (frag-major; idx = kc*4 + mt*2 + hf):
  // LDS[idx*1024 + lane*16] <- x[gt*32 + mt*16 + ln][bytes kc*128 + q*32 + hf*16]
  #define STAGE(buf, gt)                                                            \
    { _Pragma("unroll")                                                             \
      for (int i = 0; i < 4; ++i) {                                                 \
        const int idx = w * 4 + i;                                                  \
        const int kc_ = idx >> 2, mt_ = (idx >> 1) & 1, hf_ = idx & 1;              \
        const char* src = (const char*)x                                            \
            + (size_t)((gt) * TR + mt_ * 16 + ln) * 1024                            \
            + kc_ * 128 + q * 32 + hf_ * 16;                                        \
        __builtin_amdgcn_global_load_lds(                                           \
            (const __attribute__((address_space(1))) void*)src,                     \
            (__attribute__((address_space(3))) void*)                               \
                (xbuf + (buf) * 32768 + idx * 1024 + lane * 16),                    \
            16, 0, 0);                                                              \
      } }

  STAGE(0, gt0);

  #pragma unroll 1
  for (int t = 0; t < TPB; ++t) {
    const int cur = t & 1;
    const int gt  = gt0 + t;

    if (t < TPB - 1) STAGE(cur ^ 1, gt + 1);   // next tile: queued through all of t

    __builtin_amdgcn_sched_barrier(0);
    if (t < TPB - 1) asm volatile("s_waitcnt vmcnt(4)" ::: "memory");  // t landed
    else             asm volatile("s_waitcnt vmcnt(0)" ::: "memory");
    __builtin_amdgcn_sched_barrier(0);
    __builtin_amdgcn_s_barrier();
    __builtin_amdgcn_sched_barrier(0);

    const char* xb = xbuf + cur * 32768;

    // ---- GEMM: wave (rh,cq): 16 rows x 32 cols x K=256 ----
    f32x4 acc[2];
    #pragma unroll
    for (int j = 0; j < 2; ++j) {
      acc[j][0] = b1v[j]; acc[j][1] = b1v[j]; acc[j][2] = b1v[j]; acc[j][3] = b1v[j];
    }
    #pragma unroll
    for (int kc = 0; kc < 8; ++kc) {
      const char* base = xb + (kc * 4 + rh * 2) * 1024 + lane * 16;
      float4 lo = *(const float4*)base;
      float4 hi = *(const float4*)(base + 1024);
      union { u16 v[8]; short8 s8; } t8;
      t8.v[0] = f2bf(lo.x); t8.v[1] = f2bf(lo.y); t8.v[2] = f2bf(lo.z); t8.v[3] = f2bf(lo.w);
      t8.v[4] = f2bf(hi.x); t8.v[5] = f2bf(hi.y); t8.v[6] = f2bf(hi.z); t8.v[7] = f2bf(hi.w);
      acc[0] = __builtin_amdgcn_mfma_f32_16x16x32_bf16(t8.s8, Bf[kc][0], acc[0], 0, 0, 0);
      acc[1] = __builtin_amdgcn_mfma_f32_16x16x32_bf16(t8.s8, Bf[kc][1], acc[1], 0, 0, 0);
    }

    // ---- score partials: row = rh*16 + q*4 + r, reduce tanh(h)*w2 over ln ----
    {
      float p[4];
      #pragma unroll
      for (int r = 0; r < 4; ++r) {
        float s = 0.f;
        #pragma unroll
        for (int j = 0; j < 2; ++j)
          s += (1.0f - 2.0f / (__expf(2.0f * acc[j][r]) + 1.0f)) * w2v[j];
        p[r] = s;
      }
      #pragma unroll
      for (int off = 1; off < 16; off <<= 1)
        #pragma unroll
        for (int r = 0; r < 4; ++r) p[r] += __shfl_xor(p[r], off);
      if (ln == 0) {
        #pragma unroll
        for (int r = 0; r < 4; ++r) sSc[cq][rh * 16 + q * 4 + r] = p[r];
      }
    }
    LBAR();

    // ---- tile softmax over 32 rows (wave 0; halves stay separate for off<=16) ----
    if (w == 0) {
      float v = (lane < TR)
          ? (sSc[0][lane] + sSc[1][lane] + sSc[2][lane] + sSc[3][lane]) : -3.4e38f;
      float m = v;
      #pragma unroll
      for (int off = 1; off < 32; off <<= 1) m = fmaxf(m, __shfl_xor(m, off));
      float e = (lane < TR) ? __expf(v - m) : 0.f;
      float s = e;
      #pragma unroll
      for (int off = 1; off < 32; off <<= 1) s += __shfl_xor(s, off);
      if (lane < TR) sP[lane] = e;
      if (lane == 0) { sML[0] = m; sML[1] = s; }
    }
    LBAR();

    // ---- weighted sum from the fp32 LDS tile: wave (rh,cq) covers kc=cq*2..+1 ----
    {
      const float pw = sP[rh * 16 + ln];
      #pragma unroll
      for (int kk = 0; kk < 2; ++kk) {
        const int kc = cq * 2 + kk;
        #pragma unroll
        for (int hf = 0; hf < 2; ++hf) {
          float4 v = *(const float4*)(xb + (kc * 4 + rh * 2 + hf) * 1024 + lane * 16);
          v.x *= pw; v.y *= pw; v.z *= pw; v.w *= pw;
          #pragma unroll
          for (int off = 1; off < 16; off <<= 1) {
            v.x += __shfl_xor(v.x, off);
            v.y += __shfl_xor(v.y, off);
            v.z += __shfl_xor(v.z, off);
            v.w += __shfl_xor(v.w, off);
          }
          if (ln == 0)
            *(float4*)&sO[rh][kc * 32 + q * 8 + hf * 4] = v;
        }
      }
    }
    LBAR();

    // ---- per-tile partial store (stores ride in vmcnt; waited at next top) ----
    if (tid < Cc)
      oPart[(size_t)gt * Cc + tid] = sO[0][tid] + sO[1][tid];
    if (tid == 0) { mPart[gt] = sML[0]; lPart[gt] = sML[1]; }
    LBAR();   // sO/sML reads done before next tile overwrites
  }
}

// ---- combine 256 tile-partials per batch (parallel, deterministic) ----
__global__ __launch_bounds__(256) void combine_kernel(
    const float* __restrict__ oPart, const float* __restrict__ mPart,
    const float* __restrict__ lPart, float* __restrict__ out)
{
  const int b  = blockIdx.x >> 3;
  const int cg = blockIdx.x & 7;
  const int kk = threadIdx.x >> 5;    // 0..7
  const int c  = threadIdx.x & 31;
  const int col = cg * 32 + c;

  float M = -3.4e38f;
  for (int k = 0; k < BPB; ++k) M = fmaxf(M, mPart[b * BPB + k]);
  float den = 0.f;
  for (int k = 0; k < BPB; ++k)
    den += __expf(mPart[b * BPB + k] - M) * lPart[b * BPB + k];

  float num = 0.f;
  #pragma unroll 4
  for (int j = 0; j < BPB / 8; ++j) {
    const int k = j * 8 + kk;
    float wgt = __expf(mPart[b * BPB + k] - M);
    num = fmaf(wgt, oPart[(size_t)(b * BPB + k) * Cc + col], num);
  }
  __shared__ float red[8][32];
  red[kk][c] = num;
  __syncthreads();
  if (kk == 0) {
    float s = 0.f;
    #pragma unroll
    for (int i = 0; i < 8; ++i) s += red[i][c];
    out[b * Cc + col] = s / den;
  }
}

extern "C" void kernel_launch(void* const* d_in, const int* in_sizes, int n_in,
                              void* d_out, int out_size, void* d_ws, size_t ws_size,
                              hipStream_t stream)
{
  const float* x  = (const float*)d_in[0];
  const float* W1 = (const float*)d_in[1];
  const float* b1 = (const float*)d_in[2];
  const float* w2 = (const float*)d_in[3];
  // d_in[4] = b2: unused (softmax shift-invariant)
  float* out = (float*)d_out;

  u16*   FB    = (u16*)d_ws;                                        // 64 KB
  float* oPart = (float*)((char*)d_ws + 65536);                     // 8 MB (8192x256)
  float* mPart = (float*)((char*)d_ws + 65536 + 8388608);           // 32 KB
  float* lPart = (float*)((char*)d_ws + 65536 + 8388608 + 32768);   // 32 KB

  wprep_kernel<<<16, 256, 0, stream>>>(W1, FB);
  fused_kernel<<<GRID, 512, 0, stream>>>(x, FB, b1, w2, oPart, mPart, lPart);
  combine_kernel<<<Bb * 8, 256, 0, stream>>>(oPart, mPart, lPart, out);
}

// Round 13
// 98.716 us; speedup vs baseline: 1.8403x; 1.5209x over previous
//
#include <hip/hip_runtime.h>
#include <hip/hip_bf16.h>

// AttentivePooling: B=32, S=8192, C=256, MID=128, fp32 in/out.
// out[b,c] = sum_s softmax_s( tanh(x@W1+b1)@w2 )[b,s] * x[b,s,c]   (b2 shift-invariant)
//
// R13: R7 skeleton (counted-vmcnt DMA pipeline, known-good 95us) with BM=64:
// 37KB LDS + ~80 VGPR -> 4 blocks/CU x 4 waves = 16 waves/CU, 4096 independent
// block-pipelines. Per chunk: STAGE(k+1) [2 A-DMA + 2 B-DMA]; vmcnt(4);
// s_barrier; compute; s_barrier. Prefetch never drained mid-loop.

typedef __attribute__((ext_vector_type(8))) short short8;
typedef __attribute__((ext_vector_type(4))) float f32x4;
typedef unsigned short u16;

constexpr int Bb = 32;
constexpr int Ss = 8192;
constexpr int Cc = 256;
constexpr int MIDm = 128;
constexpr int BM = 64;               // rows per block (2 row-halves x 2 mt x 16)
constexpr int BK = 32;               // fp32 cols per chunk
constexpr int NCH = Cc / BK;         // 8 chunks
constexpr int NBLK = Bb * Ss / BM;   // 4096
constexpr int BPB = Ss / BM;         // 128 partials per batch

__device__ __forceinline__ u16 f2bf(float f) {
  return __builtin_bit_cast(u16, __float2bfloat16(f));   // RNE
}

// ---- one-time prep: W fragments, frag-major (identical to R7) ----
// t = wc*2048 + kcc*256 + nt*64 + lane  -> 8 bf16 (16B):
//   n = wc*64 + nt*16 + (lane&15),  k = kcc*32 + (lane>>4)*8 + e
__global__ __launch_bounds__(256) void wprep_kernel(
    const float* __restrict__ W1, u16* __restrict__ FB)
{
  const int t    = blockIdx.x * 256 + threadIdx.x;   // 0..4095
  const int lane = t & 63;
  const int nt   = (t >> 6) & 3;
  const int kcc  = (t >> 8) & 7;
  const int wc   = (t >> 11) & 1;
  const int n    = wc * 64 + nt * 16 + (lane & 15);
  const int k0   = kcc * 32 + (lane >> 4) * 8;
  union { u16 v[8]; short8 s; } u;
  #pragma unroll
  for (int e = 0; e < 8; ++e) u.v[e] = f2bf(W1[(size_t)(k0 + e) * MIDm + n]);
  *(short8*)(FB + (size_t)t * 8) = u.s;
}

// ---- fused: counted-vmcnt DMA pipeline -> MFMA -> softmax -> weighted x ----
__global__ __launch_bounds__(256, 4) void fused_kernel(
    const float* __restrict__ x, const u16* __restrict__ FB,
    const float* __restrict__ b1, const float* __restrict__ w2,
    float* __restrict__ oPart, float* __restrict__ mPart, float* __restrict__ lPart)
{
  __shared__ __align__(16) char sXA[2][8192];   // A chunks: 64 rows x 128B, swizzled
  __shared__ __align__(16) char sB[2][8192];    // B chunks: 2 wc x 4KB frag-major
  __shared__ float sScore[2][BM];
  __shared__ float sP[BM];
  __shared__ float sO[4][Cc];
  __shared__ float sML[2];

  const int tid  = threadIdx.x;
  const int lane = tid & 63;
  const int w    = tid >> 6;
  const int wr   = w >> 1;          // row half (rows wr*32 .. +32)
  const int wc   = w & 1;           // col half (cols wc*64 .. +64)
  const int q    = lane >> 4;
  const int ln   = lane & 15;
  const int row0 = blockIdx.x * BM;

  // acc init with b1[col]: 2 mt x 4 nt
  f32x4 acc[2][4];
  #pragma unroll
  for (int nt = 0; nt < 4; ++nt) {
    float bj = b1[wc * 64 + nt * 16 + ln];
    #pragma unroll
    for (int mt = 0; mt < 2; ++mt) {
      acc[mt][nt][0] = bj; acc[mt][nt][1] = bj; acc[mt][nt][2] = bj; acc[mt][nt][3] = bj;
    }
  }

  // STAGE chunk kc into buffer buf: 2 A-DMA + 2 B-DMA per thread.
  // A: LDS byte L (row=L>>7, cb=L&127) holds global col byte cb^((row&7)<<4).
  // B: linear copy of FB's two 4KB wc-runs for this kc.
  #define STAGE_ALL(buf, kc)                                                          \
    {                                                                                 \
      _Pragma("unroll")                                                               \
      for (int r = 0; r < 2; ++r) {                                                   \
        int L   = r * 4096 + tid * 16;                                                \
        int row = L >> 7;                                                             \
        int cb  = (L & 127) ^ ((row & 7) << 4);                                       \
        const char* src = (const char*)x                                              \
            + ((size_t)(row0 + row) * Cc + (size_t)(kc) * BK) * 4 + cb;               \
        __builtin_amdgcn_global_load_lds(                                             \
            (const __attribute__((address_space(1))) void*)src,                       \
            (__attribute__((address_space(3))) void*)(&sXA[buf][0] + L),              \
            16, 0, 0);                                                                \
      }                                                                               \
      _Pragma("unroll")                                                               \
      for (int r = 0; r < 2; ++r) {                                                   \
        const char* srcb = (const char*)FB                                            \
            + ((size_t)r * 2048 + (size_t)(kc) * 256) * 16 + (size_t)tid * 16;        \
        __builtin_amdgcn_global_load_lds(                                             \
            (const __attribute__((address_space(1))) void*)srcb,                      \
            (__attribute__((address_space(3))) void*)(&sB[buf][0] + r * 4096 + tid * 16),\
            16, 0, 0);                                                                \
      }                                                                               \
    }

  // prologue: chunk 0 in flight
  STAGE_ALL(0, 0);

  #pragma unroll
  for (int kc = 0; kc < NCH; ++kc) {
    const int cur = kc & 1;
    if (kc < NCH - 1) STAGE_ALL(1 - cur, kc + 1);

    __builtin_amdgcn_sched_barrier(0);
    if (kc < NCH - 1) asm volatile("s_waitcnt vmcnt(4)" ::: "memory");  // kc landed; kc+1 flying
    else              asm volatile("s_waitcnt vmcnt(0)" ::: "memory");
    __builtin_amdgcn_sched_barrier(0);
    __builtin_amdgcn_s_barrier();
    __builtin_amdgcn_sched_barrier(0);

    // B fragments for this wave's column half
    const char* bb = &sB[cur][0] + wc * 4096 + lane * 16;
    short8 bfrag[4];
    #pragma unroll
    for (int nt = 0; nt < 4; ++nt)
      bfrag[nt] = *(const short8*)(bb + nt * 1024);

    // A fragments (swizzled read) + cvt + MFMA
    #pragma unroll
    for (int mt = 0; mt < 2; ++mt) {
      const int row = 32 * wr + 16 * mt + ln;
      const int s   = (row & 7) << 4;
      const char* base = &sXA[cur][0] + row * 128;
      float4 lo = *(const float4*)(base + ((q * 32) ^ s));
      float4 hi = *(const float4*)(base + ((q * 32 + 16) ^ s));
      union { u16 v[8]; short8 s8; } t8;
      t8.v[0] = f2bf(lo.x); t8.v[1] = f2bf(lo.y); t8.v[2] = f2bf(lo.z); t8.v[3] = f2bf(lo.w);
      t8.v[4] = f2bf(hi.x); t8.v[5] = f2bf(hi.y); t8.v[6] = f2bf(hi.z); t8.v[7] = f2bf(hi.w);
      #pragma unroll
      for (int nt = 0; nt < 4; ++nt)
        acc[mt][nt] = __builtin_amdgcn_mfma_f32_16x16x32_bf16(
            t8.s8, bfrag[nt], acc[mt][nt], 0, 0, 0);
    }

    __builtin_amdgcn_sched_barrier(0);
    __builtin_amdgcn_s_barrier();
  }

  // ---- epilogue: score[r] = sum_col tanh(h)*w2[col] ----
  float w2v[4];
  #pragma unroll
  for (int nt = 0; nt < 4; ++nt) w2v[nt] = w2[wc * 64 + nt * 16 + ln];

  float p[2][4];
  #pragma unroll
  for (int mt = 0; mt < 2; ++mt)
    #pragma unroll
    for (int r = 0; r < 4; ++r) p[mt][r] = 0.f;

  #pragma unroll
  for (int mt = 0; mt < 2; ++mt)
    #pragma unroll
    for (int nt = 0; nt < 4; ++nt)
      #pragma unroll
      for (int r = 0; r < 4; ++r)
        p[mt][r] += (1.0f - 2.0f / (__expf(2.0f * acc[mt][nt][r]) + 1.0f)) * w2v[nt];

  #pragma unroll
  for (int off = 1; off < 16; off <<= 1)
    #pragma unroll
    for (int mt = 0; mt < 2; ++mt)
      #pragma unroll
      for (int r = 0; r < 4; ++r)
        p[mt][r] += __shfl_xor(p[mt][r], off);

  if (ln == 0) {
    #pragma unroll
    for (int mt = 0; mt < 2; ++mt)
      #pragma unroll
      for (int r = 0; r < 4; ++r)
        sScore[wc][32 * wr + 16 * mt + 4 * q + r] = p[mt][r];
  }
  __syncthreads();

  // ---- block softmax over 64 rows (wave 0) ----
  if (tid < BM) sP[tid] = sScore[0][tid] + sScore[1][tid];
  __syncthreads();
  if (w == 0) {
    float v = sP[lane];
    float m = v;
    #pragma unroll
    for (int off = 1; off < 64; off <<= 1) m = fmaxf(m, __shfl_xor(m, off));
    float e = __expf(v - m);
    float s = e;
    #pragma unroll
    for (int off = 1; off < 64; off <<= 1) s += __shfl_xor(s, off);
    sP[lane] = e;
    if (lane == 0) { sML[0] = m; sML[1] = s; }
  }
  __syncthreads();

  // ---- weighted x partial: wave w covers rows w*16..+16 (L2/L3-hot re-read) ----
  const float* xo = x + (size_t)(row0 + w * 16) * Cc + lane * 4;
  float4 o = make_float4(0.f, 0.f, 0.f, 0.f);
  #pragma unroll 8
  for (int r = 0; r < 16; ++r) {
    float pw = sP[w * 16 + r];
    float4 xv = *(const float4*)(xo + (size_t)r * Cc);
    o.x = fmaf(pw, xv.x, o.x);
    o.y = fmaf(pw, xv.y, o.y);
    o.z = fmaf(pw, xv.z, o.z);
    o.w = fmaf(pw, xv.w, o.w);
  }
  *(float4*)&sO[w][lane * 4] = o;
  __syncthreads();

  oPart[(size_t)blockIdx.x * Cc + tid] =
      sO[0][tid] + sO[1][tid] + sO[2][tid] + sO[3][tid];
  if (tid == 0) { mPart[blockIdx.x] = sML[0]; lPart[blockIdx.x] = sML[1]; }
}

// ---- combine 128 block-partials per batch (parallel, deterministic) ----
__global__ __launch_bounds__(256) void combine_kernel(
    const float* __restrict__ oPart, const float* __restrict__ mPart,
    const float* __restrict__ lPart, float* __restrict__ out)
{
  const int b   = blockIdx.x >> 3;
  const int cg  = blockIdx.x & 7;
  const int kk  = threadIdx.x >> 5;   // 0..7
  const int c   = threadIdx.x & 31;
  const int col = cg * 32 + c;

  float M = -3.4e38f;
  for (int k = 0; k < BPB; ++k) M = fmaxf(M, mPart[b * BPB + k]);
  float den = 0.f;
  for (int k = 0; k < BPB; ++k)
    den += __expf(mPart[b * BPB + k] - M) * lPart[b * BPB + k];

  float num = 0.f;
  #pragma unroll 4
  for (int j = 0; j < BPB / 8; ++j) {
    const int k = j * 8 + kk;
    float wgt = __expf(mPart[b * BPB + k] - M);
    num = fmaf(wgt, oPart[(size_t)(b * BPB + k) * Cc + col], num);
  }
  __shared__ float red[8][32];
  red[kk][c] = num;
  __syncthreads();
  if (kk == 0) {
    float s = 0.f;
    #pragma unroll
    for (int i = 0; i < 8; ++i) s += red[i][c];
    out[b * Cc + col] = s / den;
  }
}

extern "C" void kernel_launch(void* const* d_in, const int* in_sizes, int n_in,
                              void* d_out, int out_size, void* d_ws, size_t ws_size,
                              hipStream_t stream)
{
  const float* x  = (const float*)d_in[0];
  const float* W1 = (const float*)d_in[1];
  const float* b1 = (const float*)d_in[2];
  const float* w2 = (const float*)d_in[3];
  // d_in[4] = b2: unused (softmax shift-invariant)
  float* out = (float*)d_out;

  u16*   FB    = (u16*)d_ws;                                        // 64 KB
  float* oPart = (float*)((char*)d_ws + 65536);                     // 4 MB (4096x256)
  float* mPart = (float*)((char*)d_ws + 65536 + 4194304);           // 16 KB
  float* lPart = (float*)((char*)d_ws + 65536 + 4194304 + 16384);   // 16 KB

  wprep_kernel<<<16, 256, 0, stream>>>(W1, FB);
  fused_kernel<<<NBLK, 256, 0, stream>>>(x, FB, b1, w2, oPart, mPart, lPart);
  combine_kernel<<<Bb * 8, 256, 0, stream>>>(oPart, mPart, lPart, out);
}